// Round 1
// baseline (196.857 us; speedup 1.0000x reference)
//
#include <hip/hip_runtime.h>
#include <math.h>

// Fused copy + n-gram ban in ONE dispatch.
//
// Layout: flat float output of total_f = R*V elements. Each block owns a
// contiguous chunk of CHUNK4 float4s (8192 floats). Since 8192 < V (50257),
// a chunk overlaps at most 2 rows.
//
// Per block:
//   phase 1: copy the chunk (float4, coalesced, 8 iters/thread).
//   phase 2: scan the ngram windows of the (<=2) rows overlapping the chunk;
//            banned positions landing inside THIS chunk go to an LDS list.
//            (tokens are 2 MB total, L2-resident; scan overlaps other
//            blocks' copy traffic.)
//   phase 3: __syncthreads(), then write -inf at the listed positions.
// The ban writes only touch positions this same block copied, so one
// block-local barrier fully orders copy-before-ban. No second kernel.
//
// Worst case bans per chunk = 2 rows * num_windows(1020) = 2040 <= 2048.

#define CHUNK4   2048          // float4s per block (8192 floats)
#define MAX_BANS 2048          // LDS slots (8 KiB) — covers worst case

__global__ void __launch_bounds__(256)
ngram_fused(const float4* __restrict__ in4, float4* __restrict__ out4,
            const float* __restrict__ in, float* __restrict__ out,
            const int* __restrict__ tokens,
            const int* __restrict__ bsz_p, const int* __restrict__ step_p,
            const int* __restrict__ beam_p, const int* __restrict__ n_p,
            long long tok_elems, int total_f, int n4) {
    __shared__ int s_cnt;
    __shared__ int s_ban[MAX_BANS];

    const int b  = blockIdx.x;
    const int t  = threadIdx.x;
    const int lo4 = b * CHUNK4;
    const int hi4 = (lo4 + CHUNK4 < n4) ? lo4 + CHUNK4 : n4;

    if (t == 0) s_cnt = 0;
    __syncthreads();   // s_cnt visible before any atomicAdd in phase 2

    // ---- phase 1: copy (starts the BW stream immediately) ----
    for (int i = lo4 + t; i < hi4; i += 256) {
        out4[i] = in4[i];
    }
    // tail (total_f % 4) handled by the last block; 0 for this shape
    if (b == gridDim.x - 1) {
        int tf = n4 * 4 + t;
        if (tf < total_f) out[tf] = in[tf];
    }

    // ---- phase 2: window scan for rows overlapping this chunk ----
    const int bsz  = *bsz_p;
    const int step = *step_p;
    const int beam = *beam_p;
    const int n    = *n_p;

    const int R = bsz * beam;
    const long long S = tok_elems / R;
    const int V = total_f / R;
    const int num_windows = step - n + 2;
    const int last_start  = step - n + 2;
    const int L = n - 1;

    const int flo = lo4 * 4;
    const int fhi = (b == gridDim.x - 1) ? total_f : hi4 * 4;

    const int r0 = flo / V;
    const int r1 = (fhi - 1) / V;

    for (int r = r0; r <= r1; ++r) {
        const int* __restrict__ trow = tokens + (long long)r * S;
        const int rbase = r * V;
        for (int j = t; j < num_windows; j += 256) {
            bool m = true;
            for (int k = 0; k < L; ++k) {
                m &= (trow[j + k] == trow[last_start + k]);
            }
            if (m) {
                const int banned = trow[j + n - 1];
                const int f = rbase + banned;
                if (f >= flo && f < fhi) {
                    int idx = atomicAdd(&s_cnt, 1);
                    if (idx < MAX_BANS) s_ban[idx] = f - flo;
                }
            }
        }
    }

    // ---- phase 3: ordered ban writes ----
    __syncthreads();
    const int cnt = (s_cnt < MAX_BANS) ? s_cnt : MAX_BANS;
    for (int i = t; i < cnt; i += 256) {
        out[flo + s_ban[i]] = -INFINITY;
    }
}

extern "C" void kernel_launch(void* const* d_in, const int* in_sizes, int n_in,
                              void* d_out, int out_size, void* d_ws, size_t ws_size,
                              hipStream_t stream) {
    const int*   tokens = (const int*)d_in[0];
    const float* lprobs = (const float*)d_in[1];
    const int*   bsz_p  = (const int*)d_in[2];
    const int*   step_p = (const int*)d_in[3];
    const int*   beam_p = (const int*)d_in[4];
    const int*   n_p    = (const int*)d_in[5];
    float* out = (float*)d_out;

    const int total_f = out_size;          // elements (25,731,584 here)
    const int n4      = total_f / 4;       // 6,432,896 (exact for this shape)
    const int blocks  = (n4 + CHUNK4 - 1) / CHUNK4;   // 3142

    ngram_fused<<<blocks, 256, 0, stream>>>(
        (const float4*)lprobs, (float4*)out, lprobs, out,
        tokens, bsz_p, step_p, beam_p, n_p,
        (long long)in_sizes[0], total_f, n4);
}